// Round 2
// baseline (1757.838 us; speedup 1.0000x reference)
//
#include <hip/hip_runtime.h>

#define CIN 32
#define COUT 64
#define OD0 100
#define OD1 100
#define OD2 8
#define IZ 200
#define IY 200
#define IX 16
#define NTAP 27
#define CAP 256

// ---------- rank selection: four-level 8-bit radix (LDS-aggregated) ----------

__global__ void hist8_kernel(const float* __restrict__ mask, int n, int level,
                             const int* __restrict__ state, int* __restrict__ hist) {
    __shared__ int h[256];
    h[threadIdx.x] = 0;
    __syncthreads();
    unsigned pfx = level ? (unsigned)state[0] : 0u;
    int sh = 24 - 8 * level;
    for (int i = blockIdx.x * blockDim.x + threadIdx.x; i < n; i += gridDim.x * blockDim.x) {
        unsigned bits = __float_as_uint(mask[i]);   // mask in [0,1): uint order == float order
        if (level == 0 || (bits >> (sh + 8)) == pfx)
            atomicAdd(&h[(bits >> sh) & 0xFF], 1);
    }
    __syncthreads();
    int v = h[threadIdx.x];
    if (v) atomicAdd(&hist[threadIdx.x], v);
}

// Single block, 256 threads; thread 0 scans 256 bins from LDS.
__global__ void select8_kernel(const int* __restrict__ hist, int* __restrict__ state,
                               int level, int rankConst) {
    __shared__ int sc[256];
    sc[threadIdx.x] = hist[threadIdx.x];
    __syncthreads();
    if (threadIdx.x == 0) {
        int rank = level ? state[1] : rankConst;
        unsigned pfx = level ? (unsigned)state[0] : 0u;
        int c = 0;
        for (int j = 0; j < 256; j++) {
            int hv = sc[j];
            if (rank < c + hv) {
                state[0] = (int)((pfx << 8) | (unsigned)j);
                state[1] = rank - c;
                break;
            }
            c += hv;
        }
    }
}

// ---------- gather-path helper kernels ----------

// W (27,32,64) -> Wt (27,64,32): lane-contiguous weight fragments.
__global__ void transpose_w_kernel(const float* __restrict__ W, float* __restrict__ Wt) {
    int i = blockIdx.x * blockDim.x + threadIdx.x;
    if (i >= NTAP * CIN * COUT) return;
    int cout = i % COUT;
    int rest = i / COUT;
    int cin = rest % CIN;
    int tap = rest / CIN;
    Wt[((size_t)tap * COUT + cout) * CIN + cin] = W[i];
}

// Dense input grid: head[cell] -> last point index, next[] chains collisions.
__global__ void build_grid_kernel(const int* __restrict__ coors, int n,
                                  int* __restrict__ head, int* __restrict__ next) {
    int i = blockIdx.x * blockDim.x + threadIdx.x;
    if (i >= n) return;
    const int4 c = ((const int4*)coors)[i];
    int cell = ((c.x * IZ + c.y) * IY + c.z) * IX + c.w;
    next[i] = atomicExch(&head[cell], i);
}

// ---------- main gather conv ----------
// Wave = output cell, lane = cout.
// Phase 1: lanes 0..26 each own one tap -> 27 parallel head loads + parallel
//          chain walks, pushing (point | tap<<24) into a per-wave LDS list.
// Phase 2: wave loops over compact list: broadcast feat + per-lane weight + 32 fmas.
// No cross-wave sync; no atomics on output; prune fused into the single store.

__global__ void __launch_bounds__(256)
gather_kernel(const float* __restrict__ feat, const float* __restrict__ mask,
              const float* __restrict__ Wt, const int* __restrict__ state,
              const int* __restrict__ head, const int* __restrict__ next,
              float* __restrict__ out, int numOut) {
    __shared__ int list[4][CAP];
    __shared__ int cnt[4];

    int w = threadIdx.x >> 6;
    int lane = threadIdx.x & 63;
    int cellId = blockIdx.x * 4 + w;
    if (cellId >= numOut) return;

    if (lane == 0) cnt[w] = 0;

    int ox = cellId & (OD2 - 1);
    int t = cellId >> 3;               // OD2 == 8
    int oy = t % OD1;
    t /= OD1;
    int oz = t % OD0;
    int bb = t / OD0;

    float thr = __uint_as_float((unsigned)state[0]);

    // phase 1: parallel neighborhood discovery
    int p = -1;
    if (lane < NTAP) {
        int o0 = lane / 9, o1 = (lane / 3) % 3, o2 = lane % 3;
        int pz = 2 * oz - 1 + o0;      // stride-2, pad-1: input pos = 2*oc - 1 + off
        int py = 2 * oy - 1 + o1;
        int px = 2 * ox - 1 + o2;
        if ((unsigned)pz < (unsigned)IZ && (unsigned)py < (unsigned)IY && (unsigned)px < (unsigned)IX)
            p = head[((bb * IZ + pz) * IY + py) * IX + px];
    }
    int tapHi = lane << 24;

    float acc = 0.f;
    int keep = 0;

    for (;;) {
        // push phase (divergent; LDS atomics, same-wave ordered)
        while (p >= 0) {
            int pos = atomicAdd(&cnt[w], 1);
            if (pos >= CAP) break;     // don't consume p; retry after drain
            list[w][pos] = p | tapHi;
            p = next[p];
        }
        int total = cnt[w];
        if (total > CAP) total = CAP;

        // process phase: independent iterations -> pipelined loads
        for (int i = 0; i < total; i++) {
            int e = list[w][i];
            int sp = e & 0xFFFFFF;                       // N < 2^24
            int tap = ((unsigned)e) >> 24;
            const float4* fp = (const float4*)(feat + (size_t)sp * CIN);
            const float4* wp = (const float4*)(Wt + ((size_t)tap * COUT + lane) * CIN);
            float4 f0 = fp[0], f1 = fp[1], f2 = fp[2], f3 = fp[3];
            float4 f4 = fp[4], f5 = fp[5], f6 = fp[6], f7 = fp[7];
            float4 w0 = wp[0], w1 = wp[1], w2 = wp[2], w3 = wp[3];
            float4 w4 = wp[4], w5 = wp[5], w6 = wp[6], w7 = wp[7];
            acc = fmaf(f0.x, w0.x, acc); acc = fmaf(f0.y, w0.y, acc);
            acc = fmaf(f0.z, w0.z, acc); acc = fmaf(f0.w, w0.w, acc);
            acc = fmaf(f1.x, w1.x, acc); acc = fmaf(f1.y, w1.y, acc);
            acc = fmaf(f1.z, w1.z, acc); acc = fmaf(f1.w, w1.w, acc);
            acc = fmaf(f2.x, w2.x, acc); acc = fmaf(f2.y, w2.y, acc);
            acc = fmaf(f2.z, w2.z, acc); acc = fmaf(f2.w, w2.w, acc);
            acc = fmaf(f3.x, w3.x, acc); acc = fmaf(f3.y, w3.y, acc);
            acc = fmaf(f3.z, w3.z, acc); acc = fmaf(f3.w, w3.w, acc);
            acc = fmaf(f4.x, w4.x, acc); acc = fmaf(f4.y, w4.y, acc);
            acc = fmaf(f4.z, w4.z, acc); acc = fmaf(f4.w, w4.w, acc);
            acc = fmaf(f5.x, w5.x, acc); acc = fmaf(f5.y, w5.y, acc);
            acc = fmaf(f5.z, w5.z, acc); acc = fmaf(f5.w, w5.w, acc);
            acc = fmaf(f6.x, w6.x, acc); acc = fmaf(f6.y, w6.y, acc);
            acc = fmaf(f6.z, w6.z, acc); acc = fmaf(f6.w, w6.w, acc);
            acc = fmaf(f7.x, w7.x, acc); acc = fmaf(f7.y, w7.y, acc);
            acc = fmaf(f7.z, w7.z, acc); acc = fmaf(f7.w, w7.w, acc);
            keep |= (mask[sp] >= thr) ? 1 : 0;
        }

        if (__ballot(p >= 0) == 0ULL) break;   // overflow retry (rare)
        if (lane == 0) cnt[w] = 0;
    }

    out[(size_t)cellId * COUT + lane] = keep ? acc : 0.f;
}

// ---------- legacy scatter path (fallback if workspace too small) ----------

__global__ void __launch_bounds__(256)
scatter_kernel(const float* __restrict__ feat, const int* __restrict__ coors,
               const float* __restrict__ mask, const float* __restrict__ W,
               const int* __restrict__ state, float* __restrict__ out,
               int* __restrict__ keep, int n) {
    int gid = blockIdx.x * blockDim.x + threadIdx.x;
    int wave = gid >> 6;
    int lane = threadIdx.x & 63;
    if (wave >= n) return;

    const int4 c4 = ((const int4*)coors)[wave];
    int bb = c4.x, pz = c4.y, py = c4.z, px = c4.w;

    float thr = __uint_as_float((unsigned)state[0]);
    bool imp = mask[wave] >= thr;

    int oz[2], ozo[2], nz = 0;
    int oy[2], oyo[2], ny = 0;
    int ox[2], oxo[2], nx = 0;
#pragma unroll
    for (int o = 0; o < 3; o++) {
        int num = pz + 1 - o;
        if (num >= 0 && !(num & 1) && (num >> 1) < OD0) { oz[nz] = num >> 1; ozo[nz] = o; nz++; }
        num = py + 1 - o;
        if (num >= 0 && !(num & 1) && (num >> 1) < OD1) { oy[ny] = num >> 1; oyo[ny] = o; ny++; }
        num = px + 1 - o;
        if (num >= 0 && !(num & 1) && (num >> 1) < OD2) { ox[nx] = num >> 1; oxo[nx] = o; nx++; }
    }

    float f[CIN];
    const float4* fp = (const float4*)(feat + (size_t)wave * CIN);
#pragma unroll
    for (int j = 0; j < CIN / 4; j++) {
        float4 v = fp[j];
        f[4 * j + 0] = v.x; f[4 * j + 1] = v.y; f[4 * j + 2] = v.z; f[4 * j + 3] = v.w;
    }

    for (int a = 0; a < nz; a++)
        for (int b = 0; b < ny; b++)
            for (int c = 0; c < nx; c++) {
                int woff = ((ozo[a] * 3 + oyo[b]) * 3 + oxo[c]) * (CIN * COUT);
                const float* w = W + woff + lane;
                float acc = 0.f;
#pragma unroll
                for (int k = 0; k < CIN; k++) acc = fmaf(f[k], w[k * COUT], acc);
                int lin = ((bb * OD0 + oz[a]) * OD1 + oy[b]) * OD2 + ox[c];
                atomicAdd(out + (size_t)lin * COUT + lane, acc);
                if (imp && lane == 0) keep[lin] = 1;
            }
}

__global__ void finalize_kernel(float* __restrict__ out, const int* __restrict__ keep, int numOut) {
    int t = blockIdx.x * blockDim.x + threadIdx.x;
    if (t >= numOut * (COUT / 4)) return;
    int o = t >> 4;
    if (!keep[o]) ((float4*)out)[t] = make_float4(0.f, 0.f, 0.f, 0.f);
}

extern "C" void kernel_launch(void* const* d_in, const int* in_sizes, int n_in,
                              void* d_out, int out_size, void* d_ws, size_t ws_size,
                              hipStream_t stream) {
    const float* feat  = (const float*)d_in[0];   // (N, 32) f32
    const int*   coors = (const int*)d_in[1];     // (N, 4)  i32
    const float* mask  = (const float*)d_in[2];   // (N,)    f32
    const float* W     = (const float*)d_in[3];   // (3,3,3,32,64) f32

    int n = in_sizes[2];                 // N
    int numOut = out_size / COUT;        // 160000
    int rank = (int)(n * 0.5);           // int(N * PRUNING_RATIO)

    const int blk = 256;
    int gN = (n + blk - 1) / blk;

    char* ws = (char*)d_ws;

    // workspace layout
    size_t offHist  = 0;                                   // 4 levels x 256 ints = 4 KB
    size_t offState = 4 * 256 * 4;                         // 2 ints (pad 64)
    size_t offWt    = offState + 64;                       // 27*64*32 f32 = 221184 B
    size_t offHead  = offWt + (size_t)NTAP * CIN * COUT * 4;     // 2*200*200*16 ints
    size_t offNext  = offHead + (size_t)2 * IZ * IY * IX * 4;    // n ints
    size_t need     = offNext + (size_t)n * 4;

    int* hist  = (int*)(ws + offHist);
    int* state = (int*)(ws + offState);

    if (ws_size >= need) {
        float* Wt = (float*)(ws + offWt);
        int* head = (int*)(ws + offHead);
        int* next = (int*)(ws + offNext);

        hipMemsetAsync(ws, 0, offWt, stream);                              // hists + state
        hipMemsetAsync(head, 0xFF, (size_t)2 * IZ * IY * IX * 4, stream);  // head = -1

        // 4-level 8-bit radix rank selection
        for (int lvl = 0; lvl < 4; lvl++) {
            hist8_kernel<<<256, blk, 0, stream>>>(mask, n, lvl, state, hist + lvl * 256);
            select8_kernel<<<1, 256, 0, stream>>>(hist + lvl * 256, state, lvl, rank);
        }

        int wElems = NTAP * CIN * COUT;
        transpose_w_kernel<<<(wElems + blk - 1) / blk, blk, 0, stream>>>(W, Wt);
        build_grid_kernel<<<gN, blk, 0, stream>>>(coors, n, head, next);

        int gGather = (numOut + 3) / 4;    // 4 waves (cells) per block
        gather_kernel<<<gGather, blk, 0, stream>>>(feat, mask, Wt, state,
                                                   head, next, (float*)d_out, numOut);
    } else {
        // legacy scatter path
        int* keep = (int*)(ws + offWt);
        hipMemsetAsync(d_out, 0, (size_t)out_size * sizeof(float), stream);
        hipMemsetAsync(ws, 0, offWt + (size_t)numOut * 4, stream);

        for (int lvl = 0; lvl < 4; lvl++) {
            hist8_kernel<<<256, blk, 0, stream>>>(mask, n, lvl, state, hist + lvl * 256);
            select8_kernel<<<1, 256, 0, stream>>>(hist + lvl * 256, state, lvl, rank);
        }

        long long threads = (long long)n * 64;
        int gScatter = (int)((threads + blk - 1) / blk);
        scatter_kernel<<<gScatter, blk, 0, stream>>>(feat, coors, mask, W, state,
                                                     (float*)d_out, keep, n);

        int fin = numOut * (COUT / 4);
        finalize_kernel<<<(fin + blk - 1) / blk, blk, 0, stream>>>((float*)d_out, keep, numOut);
    }
}

// Round 3
// 1093.372 us; speedup vs baseline: 1.6077x; 1.6077x over previous
//
#include <hip/hip_runtime.h>

#define CIN 32
#define COUT 64
#define OD0 100
#define OD1 100
#define OD2 8
#define IZ 200
#define IY 200
#define IX 16
#define NTAP 27
#define NCELLS (2 * IZ * IY * IX)   // 1,280,000  (divisible by 1024)
#define TOY 4
#define TOX 8

// ---------- rank selection: four-level 8-bit radix (LDS-aggregated) ----------

__global__ void hist8_kernel(const float* __restrict__ mask, int n, int level,
                             const int* __restrict__ state, int* __restrict__ hist) {
    __shared__ int h[256];
    h[threadIdx.x] = 0;
    __syncthreads();
    unsigned pfx = level ? (unsigned)state[0] : 0u;
    int sh = 24 - 8 * level;
    for (int i = blockIdx.x * blockDim.x + threadIdx.x; i < n; i += gridDim.x * blockDim.x) {
        unsigned bits = __float_as_uint(mask[i]);   // mask in [0,1): uint order == float order
        if (level == 0 || (bits >> (sh + 8)) == pfx)
            atomicAdd(&h[(bits >> sh) & 0xFF], 1);
    }
    __syncthreads();
    int v = h[threadIdx.x];
    if (v) atomicAdd(&hist[threadIdx.x], v);
}

__global__ void select8_kernel(const int* __restrict__ hist, int* __restrict__ state,
                               int level, int rankConst) {
    __shared__ int sc[256];
    sc[threadIdx.x] = hist[threadIdx.x];
    __syncthreads();
    if (threadIdx.x == 0) {
        int rank = level ? state[1] : rankConst;
        unsigned pfx = level ? (unsigned)state[0] : 0u;
        int c = 0;
        for (int j = 0; j < 256; j++) {
            int hv = sc[j];
            if (rank < c + hv) {
                state[0] = (int)((pfx << 8) | (unsigned)j);
                state[1] = rank - c;
                break;
            }
            c += hv;
        }
    }
}

// ---------- W (27,32,64) -> Wt (27,64,32): lane-contiguous weight columns ----------

__global__ void transpose_w_kernel(const float* __restrict__ W, float* __restrict__ Wt) {
    int i = blockIdx.x * blockDim.x + threadIdx.x;
    if (i >= NTAP * CIN * COUT) return;
    int cout = i % COUT;
    int rest = i / COUT;
    int cin = rest % CIN;
    int tap = rest / CIN;
    Wt[((size_t)tap * COUT + cout) * CIN + cin] = W[i];
}

// ---------- CSR build over dense input cells ----------

__global__ void count_kernel(const int* __restrict__ coors, int n, int* __restrict__ S) {
    int i = blockIdx.x * blockDim.x + threadIdx.x;
    if (i >= n) return;
    const int4 c = ((const int4*)coors)[i];
    int cell = ((c.x * IZ + c.y) * IY + c.z) * IX + c.w;
    atomicAdd(&S[cell], 1);
}

// exclusive scan over NCELLS ints: 1024 elems / block
__global__ void scan_l0_kernel(int* __restrict__ S, int* __restrict__ partials) {
    __shared__ int ts[256];
    int tid = threadIdx.x;
    int base = blockIdx.x * 1024 + tid * 4;
    int4 v = ((int4*)S)[blockIdx.x * 256 + tid];
    int s1 = v.x + v.y, s2 = s1 + v.z, s3 = s2 + v.w;
    ts[tid] = s3;
    __syncthreads();
    for (int off = 1; off < 256; off <<= 1) {
        int t = (tid >= off) ? ts[tid - off] : 0;
        __syncthreads();
        ts[tid] += t;
        __syncthreads();
    }
    int excl = ts[tid] - s3;
    int4 o;
    o.x = excl; o.y = excl + v.x; o.z = excl + s1; o.w = excl + s2;
    ((int4*)S)[blockIdx.x * 256 + tid] = o;
    if (tid == 255) partials[blockIdx.x] = ts[255];
    (void)base;
}

__global__ void scan_l1_kernel(int* __restrict__ partials, int nP) {
    __shared__ int sums[256];
    int tid = threadIdx.x;
    int per = (nP + 255) / 256;
    int lo = tid * per, hi = lo + per;
    if (hi > nP) hi = nP;
    int s = 0;
    for (int j = lo; j < hi; j++) s += partials[j];
    sums[tid] = s;
    __syncthreads();
    for (int off = 1; off < 256; off <<= 1) {
        int t = (tid >= off) ? sums[tid - off] : 0;
        __syncthreads();
        sums[tid] += t;
        __syncthreads();
    }
    int run = sums[tid] - s;
    for (int j = lo; j < hi; j++) { int v = partials[j]; partials[j] = run; run += v; }
}

__global__ void scan_l2_kernel(int* __restrict__ S, const int* __restrict__ partials) {
    int add = partials[blockIdx.x];
    if (add == 0) return;
    int4 v = ((int4*)S)[blockIdx.x * 256 + threadIdx.x];
    v.x += add; v.y += add; v.z += add; v.w += add;
    ((int4*)S)[blockIdx.x * 256 + threadIdx.x] = v;
}

// scatter point ids; S[c] becomes end-of-range (range c = [S[c-1], S[c]))
__global__ void scatter_points_kernel(const int* __restrict__ coors, const float* __restrict__ mask,
                                      const int* __restrict__ state, int n,
                                      int* __restrict__ S, int* __restrict__ entries) {
    int i = blockIdx.x * blockDim.x + threadIdx.x;
    if (i >= n) return;
    const int4 c = ((const int4*)coors)[i];
    int cell = ((c.x * IZ + c.y) * IY + c.z) * IX + c.w;
    float thr = __uint_as_float((unsigned)state[0]);
    int imp = (mask[i] >= thr) ? 1 : 0;
    int pos = atomicAdd(&S[cell], 1);
    entries[pos] = (i << 1) | imp;
}

// ---------- main conv: block = 4x8 output tile, tap-uniform waves ----------
// Per tap: weight column held in registers; CSR ranges swept with 8-way unroll;
// per-cell accumulate in registers, one LDS atomicAdd per nonempty (tap,cell).
// Single coalesced store per cell; prune fused. No global atomics, no chains.

__global__ void __launch_bounds__(256)
conv_kernel(const float* __restrict__ feat, const float* __restrict__ Wt,
            const int* __restrict__ S, const int* __restrict__ entries,
            float* __restrict__ out) {
    __shared__ float accS[TOY * TOX][COUT];   // 8 KB
    __shared__ int keepS[TOY * TOX];

    int tid = threadIdx.x;
    int w = tid >> 6;
    int lane = tid & 63;

    {   // zero 2048 floats + flags
        float4 z = make_float4(0.f, 0.f, 0.f, 0.f);
        float4* a4 = (float4*)&accS[0][0];
        a4[tid] = z;
        a4[tid + 256] = z;
        if (tid < TOY * TOX) keepS[tid] = 0;
    }
    __syncthreads();

    int tile = blockIdx.x;
    int oyT = (tile % (OD1 / TOY)) * TOY;
    int rest = tile / (OD1 / TOY);
    int oz = rest % OD0;
    int bb = rest / OD0;

    for (int t = w; t < NTAP; t += 4) {
        int o0 = t / 9, o1 = (t / 3) % 3, o2 = t % 3;
        int pz = 2 * oz - 1 + o0;          // high side never clips (max = 199)
        if (pz < 0) continue;

        const float4* wp = (const float4*)(Wt + ((size_t)t * COUT + lane) * CIN);
        float4 w0 = wp[0], w1 = wp[1], w2 = wp[2], w3 = wp[3];
        float4 w4 = wp[4], w5 = wp[5], w6 = wp[6], w7 = wp[7];

        int zbase = (bb * IZ + pz) * IY;
        for (int yy = 0; yy < TOY; yy++) {
            int oy = oyT + yy;
            int py = 2 * oy - 1 + o1;
            if (py < 0) continue;
            int rowbase = (zbase + py) * IX;
            int px0 = o2 - 1;
#pragma unroll
            for (int ox = 0; ox < TOX; ox++) {
                int px = px0 + 2 * ox;
                if (px < 0) continue;       // only ox=0, o2=0
                int cidx = rowbase + px;
                int rs = (cidx > 0) ? S[cidx - 1] : 0;
                int re = S[cidx];
                if (re <= rs) continue;
                float a0 = 0.f, a1 = 0.f, a2 = 0.f, a3 = 0.f;
                int keepBit = 0;
                for (int i = rs; i < re; i++) {
                    int e = entries[i];
                    keepBit |= (e & 1);
                    const float4* fp = (const float4*)(feat + (size_t)(e >> 1) * CIN);
                    float4 f0 = fp[0], f1 = fp[1], f2 = fp[2], f3 = fp[3];
                    float4 f4 = fp[4], f5 = fp[5], f6 = fp[6], f7 = fp[7];
                    a0 = fmaf(f0.x, w0.x, a0); a0 = fmaf(f0.y, w0.y, a0);
                    a0 = fmaf(f0.z, w0.z, a0); a0 = fmaf(f0.w, w0.w, a0);
                    a1 = fmaf(f1.x, w1.x, a1); a1 = fmaf(f1.y, w1.y, a1);
                    a1 = fmaf(f1.z, w1.z, a1); a1 = fmaf(f1.w, w1.w, a1);
                    a2 = fmaf(f2.x, w2.x, a2); a2 = fmaf(f2.y, w2.y, a2);
                    a2 = fmaf(f2.z, w2.z, a2); a2 = fmaf(f2.w, w2.w, a2);
                    a3 = fmaf(f3.x, w3.x, a3); a3 = fmaf(f3.y, w3.y, a3);
                    a3 = fmaf(f3.z, w3.z, a3); a3 = fmaf(f3.w, w3.w, a3);
                    a0 = fmaf(f4.x, w4.x, a0); a0 = fmaf(f4.y, w4.y, a0);
                    a0 = fmaf(f4.z, w4.z, a0); a0 = fmaf(f4.w, w4.w, a0);
                    a1 = fmaf(f5.x, w5.x, a1); a1 = fmaf(f5.y, w5.y, a1);
                    a1 = fmaf(f5.z, w5.z, a1); a1 = fmaf(f5.w, w5.w, a1);
                    a2 = fmaf(f6.x, w6.x, a2); a2 = fmaf(f6.y, w6.y, a2);
                    a2 = fmaf(f6.z, w6.z, a2); a2 = fmaf(f6.w, w6.w, a2);
                    a3 = fmaf(f7.x, w7.x, a3); a3 = fmaf(f7.y, w7.y, a3);
                    a3 = fmaf(f7.z, w7.z, a3); a3 = fmaf(f7.w, w7.w, a3);
                }
                int cl = yy * TOX + ox;
                atomicAdd(&accS[cl][lane], (a0 + a1) + (a2 + a3));
                if (lane == 0 && keepBit) keepS[cl] = 1;
            }
        }
    }
    __syncthreads();

    // epilogue: wave w stores cells w*8 .. w*8+7, coalesced 256B per cell
#pragma unroll
    for (int k = 0; k < 8; k++) {
        int cl = w * 8 + k;
        int oy = oyT + (cl >> 3);
        int ox = cl & 7;
        size_t cellG = (((size_t)bb * OD0 + oz) * OD1 + oy) * OD2 + ox;
        out[cellG * COUT + lane] = keepS[cl] ? accS[cl][lane] : 0.f;
    }
}

// ---------- legacy scatter path (fallback if workspace too small) ----------

__global__ void __launch_bounds__(256)
scatter_kernel(const float* __restrict__ feat, const int* __restrict__ coors,
               const float* __restrict__ mask, const float* __restrict__ W,
               const int* __restrict__ state, float* __restrict__ out,
               int* __restrict__ keep, int n) {
    int gid = blockIdx.x * blockDim.x + threadIdx.x;
    int wave = gid >> 6;
    int lane = threadIdx.x & 63;
    if (wave >= n) return;

    const int4 c4 = ((const int4*)coors)[wave];
    int bb = c4.x, pz = c4.y, py = c4.z, px = c4.w;

    float thr = __uint_as_float((unsigned)state[0]);
    bool imp = mask[wave] >= thr;

    int oz[2], ozo[2], nz = 0;
    int oy[2], oyo[2], ny = 0;
    int ox[2], oxo[2], nx = 0;
#pragma unroll
    for (int o = 0; o < 3; o++) {
        int num = pz + 1 - o;
        if (num >= 0 && !(num & 1) && (num >> 1) < OD0) { oz[nz] = num >> 1; ozo[nz] = o; nz++; }
        num = py + 1 - o;
        if (num >= 0 && !(num & 1) && (num >> 1) < OD1) { oy[ny] = num >> 1; oyo[ny] = o; ny++; }
        num = px + 1 - o;
        if (num >= 0 && !(num & 1) && (num >> 1) < OD2) { ox[nx] = num >> 1; oxo[nx] = o; nx++; }
    }

    float f[CIN];
    const float4* fp = (const float4*)(feat + (size_t)wave * CIN);
#pragma unroll
    for (int j = 0; j < CIN / 4; j++) {
        float4 v = fp[j];
        f[4 * j + 0] = v.x; f[4 * j + 1] = v.y; f[4 * j + 2] = v.z; f[4 * j + 3] = v.w;
    }

    for (int a = 0; a < nz; a++)
        for (int b = 0; b < ny; b++)
            for (int c = 0; c < nx; c++) {
                int woff = ((ozo[a] * 3 + oyo[b]) * 3 + oxo[c]) * (CIN * COUT);
                const float* wcol = W + woff + lane;
                float acc = 0.f;
#pragma unroll
                for (int k = 0; k < CIN; k++) acc = fmaf(f[k], wcol[k * COUT], acc);
                int lin = ((bb * OD0 + oz[a]) * OD1 + oy[b]) * OD2 + ox[c];
                atomicAdd(out + (size_t)lin * COUT + lane, acc);
                if (imp && lane == 0) keep[lin] = 1;
            }
}

__global__ void finalize_kernel(float* __restrict__ out, const int* __restrict__ keep, int numOut) {
    int t = blockIdx.x * blockDim.x + threadIdx.x;
    if (t >= numOut * (COUT / 4)) return;
    int o = t >> 4;
    if (!keep[o]) ((float4*)out)[t] = make_float4(0.f, 0.f, 0.f, 0.f);
}

extern "C" void kernel_launch(void* const* d_in, const int* in_sizes, int n_in,
                              void* d_out, int out_size, void* d_ws, size_t ws_size,
                              hipStream_t stream) {
    const float* feat  = (const float*)d_in[0];   // (N, 32) f32
    const int*   coors = (const int*)d_in[1];     // (N, 4)  i32
    const float* mask  = (const float*)d_in[2];   // (N,)    f32
    const float* W     = (const float*)d_in[3];   // (3,3,3,32,64) f32

    int n = in_sizes[2];                 // N
    int numOut = out_size / COUT;        // 160000
    int rank = (int)(n * 0.5);           // int(N * PRUNING_RATIO)

    const int blk = 256;
    int gN = (n + blk - 1) / blk;

    char* ws = (char*)d_ws;

    // workspace layout
    size_t offHist    = 0;                                   // 4 x 256 ints = 4 KB
    size_t offState   = 4 * 256 * 4;                         // 64 B
    size_t offS       = offState + 64;                       // NCELLS ints = 5.12 MB (16B aligned)
    size_t offPart    = offS + (size_t)NCELLS * 4;           // 1250 ints (pad to 64)
    size_t offEntries = offPart + 1280 * 4;                  // n ints
    size_t offWt      = offEntries + (size_t)n * 4;          // 27*64*32 f32
    size_t need       = offWt + (size_t)NTAP * CIN * COUT * 4;

    int* hist  = (int*)(ws + offHist);
    int* state = (int*)(ws + offState);

    if (ws_size >= need) {
        int*   S       = (int*)(ws + offS);
        int*   part    = (int*)(ws + offPart);
        int*   entries = (int*)(ws + offEntries);
        float* Wt      = (float*)(ws + offWt);

        // zero hist+state+S in one memset (contiguous)
        hipMemsetAsync(ws, 0, offS + (size_t)NCELLS * 4, stream);

        // rank selection (4-level 8-bit radix)
        for (int lvl = 0; lvl < 4; lvl++) {
            hist8_kernel<<<256, blk, 0, stream>>>(mask, n, lvl, state, hist + lvl * 256);
            select8_kernel<<<1, 256, 0, stream>>>(hist + lvl * 256, state, lvl, rank);
        }

        int wElems = NTAP * CIN * COUT;
        transpose_w_kernel<<<(wElems + blk - 1) / blk, blk, 0, stream>>>(W, Wt);

        // CSR build
        count_kernel<<<gN, blk, 0, stream>>>(coors, n, S);
        int nBlocksScan = NCELLS / 1024;                     // 1250
        scan_l0_kernel<<<nBlocksScan, 256, 0, stream>>>(S, part);
        scan_l1_kernel<<<1, 256, 0, stream>>>(part, nBlocksScan);
        scan_l2_kernel<<<nBlocksScan, 256, 0, stream>>>(S, part);
        scatter_points_kernel<<<gN, blk, 0, stream>>>(coors, mask, state, n, S, entries);

        // conv: 4x8 output tiles
        int nTiles = numOut / (TOY * TOX);                   // 5000
        conv_kernel<<<nTiles, 256, 0, stream>>>(feat, Wt, S, entries, (float*)d_out);
    } else {
        // legacy scatter path
        int* keep = (int*)(ws + offS);
        hipMemsetAsync(d_out, 0, (size_t)out_size * sizeof(float), stream);
        hipMemsetAsync(ws, 0, offS + (size_t)numOut * 4, stream);

        for (int lvl = 0; lvl < 4; lvl++) {
            hist8_kernel<<<256, blk, 0, stream>>>(mask, n, lvl, state, hist + lvl * 256);
            select8_kernel<<<1, 256, 0, stream>>>(hist + lvl * 256, state, lvl, rank);
        }

        long long threads = (long long)n * 64;
        int gScatter = (int)((threads + blk - 1) / blk);
        scatter_kernel<<<gScatter, blk, 0, stream>>>(feat, coors, mask, W, state,
                                                     (float*)d_out, keep, n);

        int fin = numOut * (COUT / 4);
        finalize_kernel<<<(fin + blk - 1) / blk, blk, 0, stream>>>((float*)d_out, keep, numOut);
    }
}

// Round 4
// 736.103 us; speedup vs baseline: 2.3880x; 1.4854x over previous
//
#include <hip/hip_runtime.h>

#define CIN 32
#define COUT 64
#define OD0 100
#define OD1 100
#define OD2 8
#define IZ 200
#define IY 200
#define IX 16
#define NTAP 27
#define NCELLS (2 * IZ * IY * IX)   // 1,280,000  (divisible by 1024)
#define TOY 4
#define TOX 8
#define NROW 27                      // 3 planes x 9 y-rows
#define NCELL_R (NROW * 16)          // 432 region cells
#define CAPB 384                     // per-bin worklist capacity (avg ~23)

// ---------- rank selection: four-level 8-bit radix (LDS-aggregated) ----------

__global__ void hist8_kernel(const float* __restrict__ mask, int n, int level,
                             const int* __restrict__ state, int* __restrict__ hist) {
    __shared__ int h[256];
    h[threadIdx.x] = 0;
    __syncthreads();
    unsigned pfx = level ? (unsigned)state[0] : 0u;
    int sh = 24 - 8 * level;
    for (int i = blockIdx.x * blockDim.x + threadIdx.x; i < n; i += gridDim.x * blockDim.x) {
        unsigned bits = __float_as_uint(mask[i]);   // mask in [0,1): uint order == float order
        if (level == 0 || (bits >> (sh + 8)) == pfx)
            atomicAdd(&h[(bits >> sh) & 0xFF], 1);
    }
    __syncthreads();
    int v = h[threadIdx.x];
    if (v) atomicAdd(&hist[threadIdx.x], v);
}

__global__ void select8_kernel(const int* __restrict__ hist, int* __restrict__ state,
                               int level, int rankConst) {
    __shared__ int sc[256];
    sc[threadIdx.x] = hist[threadIdx.x];
    __syncthreads();
    if (threadIdx.x == 0) {
        int rank = level ? state[1] : rankConst;
        unsigned pfx = level ? (unsigned)state[0] : 0u;
        int c = 0;
        for (int j = 0; j < 256; j++) {
            int hv = sc[j];
            if (rank < c + hv) {
                state[0] = (int)((pfx << 8) | (unsigned)j);
                state[1] = rank - c;
                break;
            }
            c += hv;
        }
    }
}

// ---------- W (27,32,64) -> Wt (27,64,32): lane-contiguous weight columns ----------

__global__ void transpose_w_kernel(const float* __restrict__ W, float* __restrict__ Wt) {
    int i = blockIdx.x * blockDim.x + threadIdx.x;
    if (i >= NTAP * CIN * COUT) return;
    int cout = i % COUT;
    int rest = i / COUT;
    int cin = rest % CIN;
    int tap = rest / CIN;
    Wt[((size_t)tap * COUT + cout) * CIN + cin] = W[i];
}

// ---------- CSR build over dense input cells ----------

__global__ void count_kernel(const int* __restrict__ coors, int n, int* __restrict__ S) {
    int i = blockIdx.x * blockDim.x + threadIdx.x;
    if (i >= n) return;
    const int4 c = ((const int4*)coors)[i];
    int cell = ((c.x * IZ + c.y) * IY + c.z) * IX + c.w;
    atomicAdd(&S[cell], 1);
}

__global__ void scan_l0_kernel(int* __restrict__ S, int* __restrict__ partials) {
    __shared__ int ts[256];
    int tid = threadIdx.x;
    int4 v = ((int4*)S)[blockIdx.x * 256 + tid];
    int s1 = v.x + v.y, s2 = s1 + v.z, s3 = s2 + v.w;
    ts[tid] = s3;
    __syncthreads();
    for (int off = 1; off < 256; off <<= 1) {
        int t = (tid >= off) ? ts[tid - off] : 0;
        __syncthreads();
        ts[tid] += t;
        __syncthreads();
    }
    int excl = ts[tid] - s3;
    int4 o;
    o.x = excl; o.y = excl + v.x; o.z = excl + s1; o.w = excl + s2;
    ((int4*)S)[blockIdx.x * 256 + tid] = o;
    if (tid == 255) partials[blockIdx.x] = ts[255];
}

__global__ void scan_l1_kernel(int* __restrict__ partials, int nP) {
    __shared__ int sums[256];
    int tid = threadIdx.x;
    int per = (nP + 255) / 256;
    int lo = tid * per, hi = lo + per;
    if (hi > nP) hi = nP;
    int s = 0;
    for (int j = lo; j < hi; j++) s += partials[j];
    sums[tid] = s;
    __syncthreads();
    for (int off = 1; off < 256; off <<= 1) {
        int t = (tid >= off) ? sums[tid - off] : 0;
        __syncthreads();
        sums[tid] += t;
        __syncthreads();
    }
    int run = sums[tid] - s;
    for (int j = lo; j < hi; j++) { int v = partials[j]; partials[j] = run; run += v; }
}

__global__ void scan_l2_kernel(int* __restrict__ S, const int* __restrict__ partials) {
    int add = partials[blockIdx.x];
    if (add == 0) return;
    int4 v = ((int4*)S)[blockIdx.x * 256 + threadIdx.x];
    v.x += add; v.y += add; v.z += add; v.w += add;
    ((int4*)S)[blockIdx.x * 256 + threadIdx.x] = v;
}

// scatter point ids; S[c] becomes end-of-range (range c = [S[c-1], S[c]))
__global__ void scatter_points_kernel(const int* __restrict__ coors, const float* __restrict__ mask,
                                      const int* __restrict__ state, int n,
                                      int* __restrict__ S, int* __restrict__ entries) {
    int i = blockIdx.x * blockDim.x + threadIdx.x;
    if (i >= n) return;
    const int4 c = ((const int4*)coors)[i];
    int cell = ((c.x * IZ + c.y) * IY + c.z) * IX + c.w;
    float thr = __uint_as_float((unsigned)state[0]);
    int imp = (mask[i] >= thr) ? 1 : 0;
    int pos = atomicAdd(&S[cell], 1);
    entries[pos] = (i << 1) | imp;
}

// ---------- main conv ----------
// Block = 4x8 output tile at fixed (bb, oz). Input region = 3 planes x 9 rows x 16.
// Phase 0: cooperative coalesced load of region S into LDS (459 ints).
// Phase 1: threads own cells, enumerate points (parallel entries loads), push
//          packed (pid|imp|pyL|px) into 6 LDS bins keyed by (plane, pyL&1).
// Phase 2: waves take taps round-robin; weight column in regs; scan matching
//          bin; hits: broadcast feat + 32 fma + conflict-free LDS atomic.
// Epilogue: one coalesced 256B store per cell, prune fused.

__global__ void __launch_bounds__(256)
conv_kernel(const float* __restrict__ feat, const float* __restrict__ Wt,
            const int* __restrict__ S, const int* __restrict__ entries,
            float* __restrict__ out) {
    __shared__ float accS[TOY * TOX][COUT];       // 8 KB
    __shared__ int   keepS[TOY * TOX];
    __shared__ int   sLds[NROW][17];              // region S values (1836 B)
    __shared__ unsigned work[6][CAPB];            // 9 KB
    __shared__ int   cnt[6];
    __shared__ int   notDone;

    int tid = threadIdx.x;
    int w = tid >> 6;
    int lane = tid & 63;

    int tile = blockIdx.x;
    int oyT = (tile % (OD1 / TOY)) * TOY;
    int rest = tile / (OD1 / TOY);
    int oz = rest % OD0;
    int bb = rest / OD0;

    // zero accumulators
    {
        float4 z = make_float4(0.f, 0.f, 0.f, 0.f);
        float4* a4 = (float4*)&accS[0][0];
        a4[tid] = z;
        a4[tid + 256] = z;
        if (tid < TOY * TOX) keepS[tid] = 0;
    }

    // ---- phase 0: region S -> LDS (27 rows x 17 values, coalesced) ----
    for (int idx = tid; idx < NROW * 17; idx += 256) {
        int row = idx / 17, j = idx % 17;
        int plane = row / 9, pyL = row % 9;
        int pz = 2 * oz - 1 + plane;
        int py = 2 * oyT - 1 + pyL;
        int v = 0;
        if (pz >= 0 && py >= 0) {                 // upper bounds never exceeded
            int cellFlat = ((bb * IZ + pz) * IY + py) * IX + (j - 1);
            if (cellFlat >= 0) v = S[cellFlat];
        }
        sLds[row][j] = v;
    }
    __syncthreads();

    // per-thread enumeration state (overflow-safe resume)
    int myCl[2]; int nMy = 0;
    for (int cl = tid; cl < NCELL_R; cl += 256) myCl[nMy++] = cl;
    int ci = 0;
    int pi = -1;    // next global entry index within current cell; -1 = from range start

    for (;;) {
        if (tid < 6) cnt[tid] = 0;
        if (tid == 0) notDone = 0;
        __syncthreads();

        // ---- phase 1: enumerate points into 6 bins ----
        while (ci < nMy) {
            int cl = myCl[ci];
            int row = cl >> 4, px = cl & 15;
            int rs = (pi < 0) ? sLds[row][px] : pi;
            int re = sLds[row][px + 1];
            int plane = row / 9, pyL = row % 9;
            int bin = plane * 2 + (pyL & 1);
            bool blocked = false;
            for (int i = rs; i < re; i++) {
                int pos = atomicAdd(&cnt[bin], 1);
                if (pos >= CAPB) { pi = i; blocked = true; break; }
                int e = entries[i];
                work[bin][pos] = ((unsigned)(e >> 1) << 9) | (unsigned)((e & 1) << 8)
                               | (unsigned)(pyL << 4) | (unsigned)px;
            }
            if (blocked) break;
            ci++; pi = -1;
        }
        if (ci < nMy) notDone = 1;   // benign same-value race
        __syncthreads();

        // ---- phase 2: tap-major compute, weights in registers ----
        for (int t = w; t < NTAP; t += 4) {
            int o0 = t / 9, r9 = t % 9, o1 = r9 / 3, o2 = r9 % 3;
            int bin = o0 * 2 + (o1 & 1);
            int nb = cnt[bin];
            if (nb > CAPB) nb = CAPB;
            if (nb == 0) continue;

            const float4* wp = (const float4*)(Wt + ((size_t)t * COUT + lane) * CIN);
            float4 w0 = wp[0], w1 = wp[1], w2 = wp[2], w3 = wp[3];
            float4 w4 = wp[4], w5 = wp[5], w6 = wp[6], w7 = wp[7];

            for (int j = 0; j < nb; j++) {
                unsigned e = work[bin][j];
                int pyL = (int)((e >> 4) & 15u);
                int px  = (int)(e & 15u);
                int yy = (pyL - o1) >> 1;              // parity guaranteed by bin
                if ((unsigned)yy >= (unsigned)TOY) continue;
                int dx = px + 1 - o2;
                if (dx & 1) continue;
                int ox = dx >> 1;
                if ((unsigned)ox >= (unsigned)TOX) continue;

                int pid = (int)(e >> 9);
                const float4* fp = (const float4*)(feat + (size_t)pid * CIN);
                float4 f0 = fp[0], f1 = fp[1], f2 = fp[2], f3 = fp[3];
                float4 f4 = fp[4], f5 = fp[5], f6 = fp[6], f7 = fp[7];
                float a0 = 0.f, a1 = 0.f, a2 = 0.f, a3 = 0.f;
                a0 = fmaf(f0.x, w0.x, a0); a0 = fmaf(f0.y, w0.y, a0);
                a0 = fmaf(f0.z, w0.z, a0); a0 = fmaf(f0.w, w0.w, a0);
                a1 = fmaf(f1.x, w1.x, a1); a1 = fmaf(f1.y, w1.y, a1);
                a1 = fmaf(f1.z, w1.z, a1); a1 = fmaf(f1.w, w1.w, a1);
                a2 = fmaf(f2.x, w2.x, a2); a2 = fmaf(f2.y, w2.y, a2);
                a2 = fmaf(f2.z, w2.z, a2); a2 = fmaf(f2.w, w2.w, a2);
                a3 = fmaf(f3.x, w3.x, a3); a3 = fmaf(f3.y, w3.y, a3);
                a3 = fmaf(f3.z, w3.z, a3); a3 = fmaf(f3.w, w3.w, a3);
                a0 = fmaf(f4.x, w4.x, a0); a0 = fmaf(f4.y, w4.y, a0);
                a0 = fmaf(f4.z, w4.z, a0); a0 = fmaf(f4.w, w4.w, a0);
                a1 = fmaf(f5.x, w5.x, a1); a1 = fmaf(f5.y, w5.y, a1);
                a1 = fmaf(f5.z, w5.z, a1); a1 = fmaf(f5.w, w5.w, a1);
                a2 = fmaf(f6.x, w6.x, a2); a2 = fmaf(f6.y, w6.y, a2);
                a2 = fmaf(f6.z, w6.z, a2); a2 = fmaf(f6.w, w6.w, a2);
                a3 = fmaf(f7.x, w7.x, a3); a3 = fmaf(f7.y, w7.y, a3);
                a3 = fmaf(f7.z, w7.z, a3); a3 = fmaf(f7.w, w7.w, a3);

                int cl = yy * TOX + ox;
                atomicAdd(&accS[cl][lane], (a0 + a1) + (a2 + a3));
                if (lane == 0 && (e & 0x100u)) keepS[cl] = 1;
            }
        }
        __syncthreads();
        if (!notDone) break;
    }

    // ---- epilogue: wave w stores cells w*8 .. w*8+7, coalesced ----
#pragma unroll
    for (int k = 0; k < 8; k++) {
        int cl = w * 8 + k;
        int oy = oyT + (cl >> 3);
        int ox = cl & 7;
        size_t cellG = (((size_t)bb * OD0 + oz) * OD1 + oy) * OD2 + ox;
        out[cellG * COUT + lane] = keepS[cl] ? accS[cl][lane] : 0.f;
    }
}

// ---------- legacy scatter path (fallback if workspace too small) ----------

__global__ void __launch_bounds__(256)
scatter_kernel(const float* __restrict__ feat, const int* __restrict__ coors,
               const float* __restrict__ mask, const float* __restrict__ W,
               const int* __restrict__ state, float* __restrict__ out,
               int* __restrict__ keep, int n) {
    int gid = blockIdx.x * blockDim.x + threadIdx.x;
    int wave = gid >> 6;
    int lane = threadIdx.x & 63;
    if (wave >= n) return;

    const int4 c4 = ((const int4*)coors)[wave];
    int bb = c4.x, pz = c4.y, py = c4.z, px = c4.w;

    float thr = __uint_as_float((unsigned)state[0]);
    bool imp = mask[wave] >= thr;

    int oz[2], ozo[2], nz = 0;
    int oy[2], oyo[2], ny = 0;
    int ox[2], oxo[2], nx = 0;
#pragma unroll
    for (int o = 0; o < 3; o++) {
        int num = pz + 1 - o;
        if (num >= 0 && !(num & 1) && (num >> 1) < OD0) { oz[nz] = num >> 1; ozo[nz] = o; nz++; }
        num = py + 1 - o;
        if (num >= 0 && !(num & 1) && (num >> 1) < OD1) { oy[ny] = num >> 1; oyo[ny] = o; ny++; }
        num = px + 1 - o;
        if (num >= 0 && !(num & 1) && (num >> 1) < OD2) { ox[nx] = num >> 1; oxo[nx] = o; nx++; }
    }

    float f[CIN];
    const float4* fp = (const float4*)(feat + (size_t)wave * CIN);
#pragma unroll
    for (int j = 0; j < CIN / 4; j++) {
        float4 v = fp[j];
        f[4 * j + 0] = v.x; f[4 * j + 1] = v.y; f[4 * j + 2] = v.z; f[4 * j + 3] = v.w;
    }

    for (int a = 0; a < nz; a++)
        for (int b = 0; b < ny; b++)
            for (int c = 0; c < nx; c++) {
                int woff = ((ozo[a] * 3 + oyo[b]) * 3 + oxo[c]) * (CIN * COUT);
                const float* wcol = W + woff + lane;
                float acc = 0.f;
#pragma unroll
                for (int k = 0; k < CIN; k++) acc = fmaf(f[k], wcol[k * COUT], acc);
                int lin = ((bb * OD0 + oz[a]) * OD1 + oy[b]) * OD2 + ox[c];
                atomicAdd(out + (size_t)lin * COUT + lane, acc);
                if (imp && lane == 0) keep[lin] = 1;
            }
}

__global__ void finalize_kernel(float* __restrict__ out, const int* __restrict__ keep, int numOut) {
    int t = blockIdx.x * blockDim.x + threadIdx.x;
    if (t >= numOut * (COUT / 4)) return;
    int o = t >> 4;
    if (!keep[o]) ((float4*)out)[t] = make_float4(0.f, 0.f, 0.f, 0.f);
}

extern "C" void kernel_launch(void* const* d_in, const int* in_sizes, int n_in,
                              void* d_out, int out_size, void* d_ws, size_t ws_size,
                              hipStream_t stream) {
    const float* feat  = (const float*)d_in[0];   // (N, 32) f32
    const int*   coors = (const int*)d_in[1];     // (N, 4)  i32
    const float* mask  = (const float*)d_in[2];   // (N,)    f32
    const float* W     = (const float*)d_in[3];   // (3,3,3,32,64) f32

    int n = in_sizes[2];                 // N
    int numOut = out_size / COUT;        // 160000
    int rank = (int)(n * 0.5);           // int(N * PRUNING_RATIO)

    const int blk = 256;
    int gN = (n + blk - 1) / blk;

    char* ws = (char*)d_ws;

    // workspace layout
    size_t offHist    = 0;                                   // 4 x 256 ints = 4 KB
    size_t offState   = 4 * 256 * 4;                         // 64 B
    size_t offS       = offState + 64;                       // NCELLS ints = 5.12 MB
    size_t offPart    = offS + (size_t)NCELLS * 4;           // 1250 ints (pad to 1280)
    size_t offEntries = offPart + 1280 * 4;                  // n ints
    size_t offWt      = offEntries + (size_t)n * 4;          // 27*64*32 f32
    size_t need       = offWt + (size_t)NTAP * CIN * COUT * 4;

    int* hist  = (int*)(ws + offHist);
    int* state = (int*)(ws + offState);

    if (ws_size >= need) {
        int*   S       = (int*)(ws + offS);
        int*   part    = (int*)(ws + offPart);
        int*   entries = (int*)(ws + offEntries);
        float* Wt      = (float*)(ws + offWt);

        hipMemsetAsync(ws, 0, offS + (size_t)NCELLS * 4, stream);   // hists + state + S

        for (int lvl = 0; lvl < 4; lvl++) {
            hist8_kernel<<<256, blk, 0, stream>>>(mask, n, lvl, state, hist + lvl * 256);
            select8_kernel<<<1, 256, 0, stream>>>(hist + lvl * 256, state, lvl, rank);
        }

        int wElems = NTAP * CIN * COUT;
        transpose_w_kernel<<<(wElems + blk - 1) / blk, blk, 0, stream>>>(W, Wt);

        count_kernel<<<gN, blk, 0, stream>>>(coors, n, S);
        int nBlocksScan = NCELLS / 1024;                     // 1250
        scan_l0_kernel<<<nBlocksScan, 256, 0, stream>>>(S, part);
        scan_l1_kernel<<<1, 256, 0, stream>>>(part, nBlocksScan);
        scan_l2_kernel<<<nBlocksScan, 256, 0, stream>>>(S, part);
        scatter_points_kernel<<<gN, blk, 0, stream>>>(coors, mask, state, n, S, entries);

        int nTiles = numOut / (TOY * TOX);                   // 5000
        conv_kernel<<<nTiles, 256, 0, stream>>>(feat, Wt, S, entries, (float*)d_out);
    } else {
        int* keep = (int*)(ws + offS);
        hipMemsetAsync(d_out, 0, (size_t)out_size * sizeof(float), stream);
        hipMemsetAsync(ws, 0, offS + (size_t)numOut * 4, stream);

        for (int lvl = 0; lvl < 4; lvl++) {
            hist8_kernel<<<256, blk, 0, stream>>>(mask, n, lvl, state, hist + lvl * 256);
            select8_kernel<<<1, 256, 0, stream>>>(hist + lvl * 256, state, lvl, rank);
        }

        long long threads = (long long)n * 64;
        int gScatter = (int)((threads + blk - 1) / blk);
        scatter_kernel<<<gScatter, blk, 0, stream>>>(feat, coors, mask, W, state,
                                                     (float*)d_out, keep, n);

        int fin = numOut * (COUT / 4);
        finalize_kernel<<<(fin + blk - 1) / blk, blk, 0, stream>>>((float*)d_out, keep, numOut);
    }
}